// Round 11
// baseline (356.698 us; speedup 1.0000x reference)
//
#include <hip/hip_runtime.h>
#include <hip/hip_bf16.h>

// CausalSelfAttention: B=4, N=2048, D=1024, H=16, HD=64. fp32 in / fp32 out.
// R18: restore R13-exact (best measured 270.6us): gemm1 = 128x256/8-wave/3-slot
//      ring/768 blocks (3 failed perturbations R14/R15/R17 confirm local optimum);
//      gemm2 = gemm_lds<2> @ 4x64. attn: + cross-kt K-prefetch (ping-pong named
//      kA/kB register sets, 2-step unrolled loop; kt+1's K loads issued under
//      kt's MFMAs — removes the exposed L2 latency at each kt top). cvt unchanged.
// ws: Kb/Qb/VT/sa 4x16.78MB = 64MiB; fast path adds wkb+wpb -> 72MiB; xb overlaps sa.

#define NSEQ 2048
#define NHEAD 16
#define DMODEL 1024
#define SCALE2 0.18033688011112042f  // 0.125 * log2(e)

typedef __attribute__((ext_vector_type(8))) short v8s;  // 8 bf16 = 4 VGPRs
typedef __attribute__((ext_vector_type(4))) float v4f;  // MFMA acc

__device__ __forceinline__ float bf2f(unsigned short u) {
    union { unsigned int i; float f; } v;
    v.i = ((unsigned int)u) << 16;
    return v.f;
}
__device__ __forceinline__ unsigned short f2bf(float f) {  // RNE
    unsigned int x = __float_as_uint(f);
    return (unsigned short)((x + 0x7fffu + ((x >> 16) & 1u)) >> 16);
}
__device__ __forceinline__ unsigned short f2bf_rh(float f) {  // round-half-up
    return (unsigned short)((__float_as_uint(f) + 0x8000u) >> 16);
}
__device__ __forceinline__ float fast_exp2(float x) {
#if __has_builtin(__builtin_amdgcn_exp2f)
    return __builtin_amdgcn_exp2f(x);
#else
    return __expf(x * 0.69314718056f);
#endif
}
__device__ __forceinline__ void gld_lds16(const unsigned short* g, unsigned short* l) {
    __builtin_amdgcn_global_load_lds(
        (const __attribute__((address_space(1))) void*)g,
        (__attribute__((address_space(3))) void*)l, 16, 0, 0);
}

// ---------------- cvt: fp32 -> bf16 for x, Wkqv (class-major permute), Wproj -------
// Wkqv in rows h*192 + cls*64 + e -> wkb rows cls*1024 + h*64 + e.
__global__ __launch_bounds__(256) void cvt_bf16(
    const float* __restrict__ x, const float* __restrict__ wk, const float* __restrict__ wp,
    unsigned short* __restrict__ xb, unsigned short* __restrict__ wkb,
    unsigned short* __restrict__ wpb)
{
    const int i = blockIdx.x * 256 + threadIdx.x;   // quad index, 3145728 total
    const float* s; unsigned short* d; int o;
    if (i < 2097152)      { s = x;  d = xb;  o = i; }
    else if (i < 2883584) {
        s = wk; d = wkb;
        const int oi  = i - 2097152;          // 0..786431
        const int row = oi >> 8, cq = oi & 255;
        const int h   = row / 192;
        const int rem = row - h * 192;
        const int cls = rem >> 6, e = rem & 63;
        float4 f = ((const float4*)s)[oi];
        ushort4 u;
        u.x = f2bf(f.x); u.y = f2bf(f.y); u.z = f2bf(f.z); u.w = f2bf(f.w);
        ((ushort4*)d)[(((cls << 10) + (h << 6) + e) << 8) + cq] = u;
        return;
    }
    else                  { s = wp; d = wpb; o = i - 2883584; }
    float4 f = ((const float4*)s)[o];
    ushort4 u;
    u.x = f2bf(f.x); u.y = f2bf(f.y); u.z = f2bf(f.z); u.w = f2bf(f.w);
    ((ushort4*)d)[o] = u;
}

// ---------------- gemm: 128x256 tile, 8 waves, 3-slot ring (R13, measured 86.7us) -
// C[M,Nc] = A[M,K] @ B[Nc,K]^T + bias. 512 thr = 8 waves (2Mx4N), per-wave 64x64.
// LDS ring: 3 slots x (A 8KB + B 16KB) = 72KB -> 2 blocks/CU. Stage tile t+2 while
// computing t; single barrier per K-step; counted vmcnt(3) (never 0 until tail).
// Requires gridDim.y == 64, grid total % 8 == 0, K >= 64.
// EPI=1: B is class-major-permuted kqv weights; split-write Kb/Qb(scaled)/VT.
// EPI=2: plain fp32 C.
template <int EPI>
__global__ __launch_bounds__(512, 4) void gemm_lds(
    const unsigned short* __restrict__ A, const unsigned short* __restrict__ B,
    const float* __restrict__ bias,
    float* __restrict__ Cf,
    unsigned short* __restrict__ Kb, unsigned short* __restrict__ Qb,
    unsigned short* __restrict__ VTb,
    int M, int Nc, int K)
{
    __shared__ __align__(16) unsigned short Al[3][4096];   // 128 rows x 32k
    __shared__ __align__(16) unsigned short Bl[3][8192];   // 256 rows x 32k

    const int t = threadIdx.x, wave = t >> 6, lane = t & 63;
    const int wm = wave >> 2, wn = wave & 3;               // 2 x 4 wave grid

    // XCD-chunked bijective swizzle: per XCD an 8-row A slab (2MB) x all bx;
    // B tile (512KB) reused 8x within the XCD's L2.
    const int lin = blockIdx.y * gridDim.x + blockIdx.x;
    const int xcd = lin & 7, pos = lin >> 3;
    const int by  = (xcd << 3) + (pos & 7);
    const int bx  = pos >> 3;
    const int m0 = by * 128, n0 = bx * 256;
    const int quad = lane >> 4, c = lane & 15;

    // staging: wave w loads A 16-row group w, B groups {2w, 2w+1}.
    const int r15 = lane & 15, kg = (lane >> 4) & 3;
    const int g0 = wave * 2, g1 = wave * 2 + 1;
    const unsigned short* sA  = A + (size_t)(m0 + wave * 16 + r15) * K + kg * 8;
    const unsigned short* sB0 = B + (size_t)(n0 + g0 * 16 + r15) * K + kg * 8;
    const unsigned short* sB1 = B + (size_t)(n0 + g1 * 16 + r15) * K + kg * 8;

    v4f acc[4][4];
#pragma unroll
    for (int i = 0; i < 4; ++i)
#pragma unroll
        for (int j = 0; j < 4; ++j) acc[i][j] = (v4f){0.f, 0.f, 0.f, 0.f};

    const int fbase = (quad * 16 + c) * 8;
    const int nt = K >> 5;   // 32-wide K tiles (K=1024 -> 32)

    auto stage = [&](int sl, int tt) {
        const int o = tt << 5;
        gld_lds16(sA  + o, &Al[sl][wave * 512]);
        gld_lds16(sB0 + o, &Bl[sl][g0 * 512]);
        gld_lds16(sB1 + o, &Bl[sl][g1 * 512]);
    };

    // prologue: tiles 0,1 staged (6 loads/thread); wait tile 0 (leave 3 in flight)
    stage(0, 0);
    stage(1, 1);
    asm volatile("s_waitcnt vmcnt(3)" ::: "memory");
    __builtin_amdgcn_s_barrier();

    int sl = 0;
    for (int tt = 0; tt < nt; ++tt) {
        const int sl2 = (sl == 0) ? 2 : sl - 1;   // (tt+2)%3
        const bool pf = (tt + 2 < nt);

        v8s af[4], bfr[4];
#pragma unroll
        for (int ms = 0; ms < 4; ++ms)
            af[ms] = *(const v8s*)&Al[sl][(wm * 4 + ms) * 512 + fbase];
#pragma unroll
        for (int ns = 0; ns < 4; ++ns)
            bfr[ns] = *(const v8s*)&Bl[sl][(wn * 4 + ns) * 512 + fbase];
        if (pf) stage(sl2, tt + 2);               // overlaps MFMA below

        __builtin_amdgcn_s_setprio(1);
#pragma unroll
        for (int ms = 0; ms < 4; ++ms)
#pragma unroll
            for (int ns = 0; ns < 4; ++ns)
                acc[ms][ns] = __builtin_amdgcn_mfma_f32_16x16x32_bf16(
                    af[ms], bfr[ns], acc[ms][ns], 0, 0, 0);
        __builtin_amdgcn_s_setprio(0);

        // retire tile tt+1's 3 loads; tile tt+2's stay in flight across the barrier
        if (pf) { asm volatile("s_waitcnt vmcnt(3)" ::: "memory"); }
        else    { asm volatile("s_waitcnt vmcnt(0)" ::: "memory"); }
        __builtin_amdgcn_s_barrier();
        sl = (sl == 2) ? 0 : sl + 1;
    }

#pragma unroll
    for (int ms = 0; ms < 4; ++ms) {
        const int row0 = m0 + wm * 64 + ms * 16 + quad * 4;
#pragma unroll
        for (int ns = 0; ns < 4; ++ns) {
            const int colbase = n0 + wn * 64 + ns * 16;   // wave-uniform, 16-aligned
            float bn, scl = 1.f;
            if (EPI == 2) {
                bn = bias[colbase + c];
            } else {
                const int cls = colbase >> 10;
                const int wi  = colbase & 1023;
                const int h   = wi >> 6, e0 = wi & 63;
                bn = bias[h * 192 + cls * 64 + e0 + c];
                if (cls == 1) scl = SCALE2;
            }
            float v0 = (acc[ms][ns][0] + bn) * scl;
            float v1 = (acc[ms][ns][1] + bn) * scl;
            float v2 = (acc[ms][ns][2] + bn) * scl;
            float v3 = (acc[ms][ns][3] + bn) * scl;
            if (EPI == 2) {
                float* pc = Cf + (size_t)row0 * Nc + colbase + c;
                pc[0] = v0; pc[(size_t)Nc] = v1;
                pc[(size_t)2 * Nc] = v2; pc[(size_t)3 * Nc] = v3;
            } else {
                const int cls = colbase >> 10;
                const int wi  = colbase & 1023;
                const int h   = wi >> 6, e = (wi & 63) + c;
                const int bb  = row0 >> 11, tok0 = row0 & 2047;
                const int bhh = bb * 16 + h;
                if (cls == 2) {            // V -> transposed [bh][dim][tok]
                    ushort4 pk;
                    pk.x = f2bf(v0); pk.y = f2bf(v1); pk.z = f2bf(v2); pk.w = f2bf(v3);
                    *(ushort4*)(VTb + ((size_t)bhh * 64 + e) * 2048 + tok0) = pk;
                } else {                   // K or Q -> [bh][tok][dim]
                    unsigned short* dst = (cls == 0) ? Kb : Qb;
                    const size_t base = ((size_t)bhh * 2048 + tok0) * 64 + e;
                    dst[base]       = f2bf(v0);
                    dst[base + 64]  = f2bf(v1);
                    dst[base + 128] = f2bf(v2);
                    dst[base + 192] = f2bf(v3);
                }
            }
        }
    }
}

// ---------------- fallback GEMM (fp32 sources, VGPR-roundtrip staging) -------------
// EPI=1 uses ORIGINAL (unpermuted) Wkqv col mapping h*192+e; scales Q by SCALE2.
template <bool A_BF16, int EPI>
__global__ __launch_bounds__(256) void gemm_mfma(
    const void* __restrict__ Av, const float* __restrict__ B,
    const float* __restrict__ bias,
    float* __restrict__ Cf,
    unsigned short* __restrict__ Kb, unsigned short* __restrict__ Qb,
    unsigned short* __restrict__ VTb,
    int M, int Nc, int K)
{
    __shared__ __align__(16) unsigned short Al[512 * 8];
    __shared__ __align__(16) unsigned short Bl[512 * 8];

    const int t = threadIdx.x;
    const int wave = t >> 6, lane = t & 63;
    const int wm = wave >> 1, wn = wave & 1;
    const int m0 = blockIdx.y * 128, n0 = blockIdx.x * 128;
    const int quad = lane >> 4, c = lane & 15;

    const int srow = t >> 1, skh = t & 1;
    const int sslot = (srow >> 4) * 64 + (skh * 2) * 16 + (srow & 15);

    v4f acc[4][4];
#pragma unroll
    for (int i = 0; i < 4; ++i)
#pragma unroll
        for (int j = 0; j < 4; ++j) acc[i][j] = (v4f){0.f, 0.f, 0.f, 0.f};

    const unsigned short* pa_u = (const unsigned short*)Av + (size_t)(m0 + srow) * K + skh * 16;
    const float*          pa_f = (const float*)Av          + (size_t)(m0 + srow) * K + skh * 16;
    const float*          pb   = B                          + (size_t)(n0 + srow) * K + skh * 16;

    const int fbase = (quad * 16 + c) * 8;

    for (int k0 = 0; k0 < K; k0 += 32) {
        unsigned short a16[16], b16[16];
        if (A_BF16) {
            uint4 r0 = *(const uint4*)(pa_u + k0);
            uint4 r1 = *(const uint4*)(pa_u + k0 + 8);
            *(uint4*)&a16[0] = r0; *(uint4*)&a16[8] = r1;
        } else {
            float4 f0 = *(const float4*)(pa_f + k0);
            float4 f1 = *(const float4*)(pa_f + k0 + 4);
            float4 f2 = *(const float4*)(pa_f + k0 + 8);
            float4 f3 = *(const float4*)(pa_f + k0 + 12);
            a16[0] = f2bf_rh(f0.x); a16[1] = f2bf_rh(f0.y); a16[2] = f2bf_rh(f0.z); a16[3] = f2bf_rh(f0.w);
            a16[4] = f2bf_rh(f1.x); a16[5] = f2bf_rh(f1.y); a16[6] = f2bf_rh(f1.z); a16[7] = f2bf_rh(f1.w);
            a16[8] = f2bf_rh(f2.x); a16[9] = f2bf_rh(f2.y); a16[10] = f2bf_rh(f2.z); a16[11] = f2bf_rh(f2.w);
            a16[12] = f2bf_rh(f3.x); a16[13] = f2bf_rh(f3.y); a16[14] = f2bf_rh(f3.z); a16[15] = f2bf_rh(f3.w);
        }
        {
            float4 g0 = *(const float4*)(pb + k0);
            float4 g1 = *(const float4*)(pb + k0 + 4);
            float4 g2 = *(const float4*)(pb + k0 + 8);
            float4 g3 = *(const float4*)(pb + k0 + 12);
            b16[0] = f2bf_rh(g0.x); b16[1] = f2bf_rh(g0.y); b16[2] = f2bf_rh(g0.z); b16[3] = f2bf_rh(g0.w);
            b16[4] = f2bf_rh(g1.x); b16[5] = f2bf_rh(g1.y); b16[6] = f2bf_rh(g1.z); b16[7] = f2bf_rh(g1.w);
            b16[8] = f2bf_rh(g2.x); b16[9] = f2bf_rh(g2.y); b16[10] = f2bf_rh(g2.z); b16[11] = f2bf_rh(g2.w);
            b16[12] = f2bf_rh(g3.x); b16[13] = f2bf_rh(g3.y); b16[14] = f2bf_rh(g3.z); b16[15] = f2bf_rh(g3.w);
        }
        __syncthreads();
        *(uint4*)&Al[sslot * 8]        = *(uint4*)&a16[0];
        *(uint4*)&Al[(sslot + 16) * 8] = *(uint4*)&a16[8];
        *(uint4*)&Bl[sslot * 8]        = *(uint4*)&b16[0];
        *(uint4*)&Bl[(sslot + 16) * 8] = *(uint4*)&b16[8];
        __syncthreads();

        v8s af[4], bf[4];
#pragma unroll
        for (int ms = 0; ms < 4; ++ms)
            af[ms] = *(const v8s*)&Al[(wm * 4 + ms) * 512 + fbase];
#pragma unroll
        for (int ns = 0; ns < 4; ++ns)
            bf[ns] = *(const v8s*)&Bl[(wn * 4 + ns) * 512 + fbase];
#pragma unroll
        for (int ms = 0; ms < 4; ++ms)
#pragma unroll
            for (int ns = 0; ns < 4; ++ns)
                acc[ms][ns] = __builtin_amdgcn_mfma_f32_16x16x32_bf16(
                    af[ms], bf[ns], acc[ms][ns], 0, 0, 0);
    }

#pragma unroll
    for (int ms = 0; ms < 4; ++ms) {
        const int row0 = m0 + wm * 64 + ms * 16 + quad * 4;
#pragma unroll
        for (int ns = 0; ns < 4; ++ns) {
            const int colbase = n0 + wn * 64 + ns * 16;
            float bn = (EPI == 2) ? bias[colbase + c] : bias[colbase + c];
            float v0 = acc[ms][ns][0] + bn;
            float v1 = acc[ms][ns][1] + bn;
            float v2 = acc[ms][ns][2] + bn;
            float v3 = acc[ms][ns][3] + bn;
            if (EPI == 2) {
                float* pc = Cf + (size_t)row0 * Nc + colbase + c;
                pc[0] = v0; pc[(size_t)Nc] = v1;
                pc[(size_t)2 * Nc] = v2; pc[(size_t)3 * Nc] = v3;
            } else {
                const int hh = colbase / 192;
                const int eb = colbase - hh * 192;
                const int bb = row0 >> 11, tok0 = row0 & 2047;
                const int bhh = bb * 16 + hh;
                if (eb >= 128) {
                    ushort4 pk;
                    pk.x = f2bf(v0); pk.y = f2bf(v1); pk.z = f2bf(v2); pk.w = f2bf(v3);
                    *(ushort4*)(VTb + ((size_t)bhh * 64 + (eb - 128) + c) * 2048 + tok0) = pk;
                } else {
                    const bool isq = (eb >= 64);
                    const float s = isq ? SCALE2 : 1.f;
                    unsigned short* dst = isq ? Qb : Kb;
                    const int e = (isq ? eb - 64 : eb) + c;
                    const size_t base = ((size_t)bhh * 2048 + tok0) * 64 + e;
                    dst[base]       = f2bf(v0 * s);
                    dst[base + 64]  = f2bf(v1 * s);
                    dst[base + 128] = f2bf(v2 * s);
                    dst[base + 192] = f2bf(v3 * s);
                }
            }
        }
    }
}

// ---------------- balanced split-K MFMA flash attention, constant-m softmax -------
// grid 512 x 256thr. bh = blockIdx&63 (XCD-grouped), bq = blockIdx>>6 (0..7).
// Constant-m softmax (P = exp2(s) raw, |s|<=46) => split-K partials just add.
// wave0: qt=bq [0,bq+1) complete + qt=31-bq [17,32-bq) tail      -> 16 kt
// wave1: qt=15-bq [0,16-bq) complete + qt=16+bq [17,17+bq) tail  -> 16 kt
// wave2: qt=16+bq [0,17) head, merges wave1's tail               -> 17 kt
// wave3: qt=31-bq [0,17) head, merges wave0's tail               -> 17 kt
// Merge via Mrg LDS (stride 81 floats -> conflict-free), one convergent barrier.
// R18: cross-kt K-prefetch — ping-pong named kA/kB register sets; kt+1's 8 K loads
// issue right after kt's V loads, retiring under kt's ~72 MFMAs.
#define ATTS 72

__global__ __launch_bounds__(256, 2) void attn_mfma(
    const unsigned short* __restrict__ Kbuf,  // [64][2048][64]
    const unsigned short* __restrict__ Qbuf,  // [64][2048][64] (scaled)
    const unsigned short* __restrict__ VT,    // [64][64][2048]
    unsigned short* __restrict__ sa)          // [8192][1024]
{
    __shared__ __align__(16) unsigned short Ps[4][64 * ATTS];   // 36,864 B
    __shared__ __align__(16) float Mrg[2][64][81];              // 41,472 B

    const int t = threadIdx.x, w = t >> 6, lane = t & 63;
    const int quad = lane >> 4, c = lane & 15;
    const int bh = blockIdx.x & 63, bq = blockIdx.x >> 6;
    const int b = bh >> 4, hh = bh & 15;
    const size_t gbase = (size_t)bh * (2048 * 64);

    const int rs  = c & 3;
    const int rc0 = (quad ^ rs) * 8, rc1 = 32 + rc0;
    unsigned short* PsW = &Ps[w][0];

    // balanced segment table (see header comment)
    const int qtA = (w == 0) ? bq : (w == 1) ? (15 - bq) : (w == 2) ? (16 + bq) : (31 - bq);
    const int kA1 = (w == 0) ? (bq + 1) : (w == 1) ? (16 - bq) : 17;
    const int qtB = (w == 0) ? (31 - bq) : (16 + bq);   // waves 0/1 only
    const int kB1 = (w == 0) ? (32 - bq) : (17 + bq);

    v4f oacc[4][4], lacc[4];
    const short oneb = (short)0x3F80;  // bf16 1.0
    const v8s ones = {oneb, oneb, oneb, oneb, oneb, oneb, oneb, oneb};
    v8s qf[4][2];

    auto loadK = [&](v8s (&kf)[4][2], int kt) {
        const int kbase = kt * 64;
#pragma unroll
        for (int kn = 0; kn < 4; ++kn) {
            const unsigned short* kp =
                Kbuf + gbase + (size_t)(kbase + kn * 16 + c) * 64 + quad * 8;
            kf[kn][0] = *(const v8s*)kp;
            kf[kn][1] = *(const v8s*)(kp + 32);
        }
    };

    // one kt step: V prefetch, (optional) K prefetch for kt+1, QK from kf regs,
    // P=exp2(s) to Ps, PV + l accumulation.
    auto step = [&](int qt, int kt, v8s (&kf)[4][2], v8s (&kpre)[4][2], bool doPre) {
        const int kbase = kt * 64;
        const bool diag = (kt == qt);   // wave-uniform

        v8s vf[4][2];
#pragma unroll
        for (int dn = 0; dn < 4; ++dn) {
            const unsigned short* vp =
                VT + gbase + (size_t)(dn * 16 + c) * 2048 + kbase + quad * 8;
            vf[dn][0] = *(const v8s*)vp;
            vf[dn][1] = *(const v8s*)(vp + 32);
        }
        if (doPre) loadK(kpre, kt + 1);

#pragma unroll
        for (int kn = 0; kn < 4; ++kn) {
#pragma unroll
            for (int qs = 0; qs < 4; ++qs) {
                v4f s = (v4f){0.f, 0.f, 0.f, 0.f};
                s = __builtin_amdgcn_mfma_f32_16x16x32_bf16(qf[qs][0], kf[kn][0], s, 0, 0, 0);
                s = __builtin_amdgcn_mfma_f32_16x16x32_bf16(qf[qs][1], kf[kn][1], s, 0, 0, 0);
                if (diag) {
#pragma unroll
                    for (int r = 0; r < 4; ++r)
                        if (kn * 16 + c > qs * 16 + quad * 4 + r) s[r] = -1e30f;
                }
#pragma unroll
                for (int r = 0; r < 4; ++r) {
                    const float p = fast_exp2(s[r]);
                    PsW[(qs * 16 + quad * 4 + r) * ATTS +
                        (((2 * kn + (c >> 3)) ^ r) * 8) + (c & 7)] = f2bf_rh(p);
                }
            }
        }
        v8s pa[4][2];
#pragma unroll
        for (int qs = 0; qs < 4; ++qs) {
            pa[qs][0] = *(const v8s*)&PsW[(qs * 16 + c) * ATTS + rc0];
            pa[qs][1] = *(const v8s*)&PsW[(qs * 16 + c) * ATTS + rc1];
        }
#pragma unroll
        for (int dn = 0; dn < 4; ++dn) {
#pragma unroll
            for (int qs = 0; qs < 4; ++qs) {
                oacc[qs][dn] = __builtin_amdgcn_mfma_f32_16x16x32_bf16(pa[qs][0], vf[dn][0], oacc[qs][dn], 0, 0, 0);
                oacc[qs][dn] = __builtin_amdgcn_mfma_f32_16x16x32_bf16(pa[qs][1], vf[dn][1], oacc[qs][dn], 0, 0, 0);
            }
        }
#pragma unroll
        for (int qs = 0; qs < 4; ++qs) {
            lacc[qs] = __builtin_amdgcn_mfma_f32_16x16x32_bf16(pa[qs][0], ones, lacc[qs], 0, 0, 0);
            lacc[qs] = __builtin_amdgcn_mfma_f32_16x16x32_bf16(pa[qs][1], ones, lacc[qs], 0, 0, 0);
        }
    };

    auto run_seg = [&](int qt, int k0, int k1) {
        const int qw = qt * 64;
#pragma unroll
        for (int qs = 0; qs < 4; ++qs) {
            const unsigned short* qp =
                Qbuf + gbase + (size_t)(qw + qs * 16 + c) * 64 + quad * 8;
            qf[qs][0] = *(const v8s*)qp;
            qf[qs][1] = *(const v8s*)(qp + 32);
        }
#pragma unroll
        for (int qs = 0; qs < 4; ++qs) {
            lacc[qs] = (v4f){0.f, 0.f, 0.f, 0.f};
#pragma unroll
            for (int dn = 0; dn < 4; ++dn) oacc[qs][dn] = (v4f){0.f, 0.f, 0.f, 0.f};
        }
        if (k0 >= k1) return;
        v8s kA[4][2], kB[4][2];
        loadK(kA, k0);
        int kt = k0;
        for (;;) {
            step(qt, kt, kA, kB, kt + 1 < k1);
            if (++kt >= k1) break;
            step(qt, kt, kB, kA, kt + 1 < k1);
            if (++kt >= k1) break;
        }
    };

    auto store_final = [&](int qt) {
        const int qw = qt * 64;
#pragma unroll
        for (int qs = 0; qs < 4; ++qs) {
            float inv[4];
#pragma unroll
            for (int r = 0; r < 4; ++r) inv[r] = 1.f / lacc[qs][r];
            const size_t obase =
                ((size_t)(b * 2048 + qw + qs * 16 + quad * 4)) * DMODEL + hh * 64;
#pragma unroll
            for (int dn = 0; dn < 4; ++dn)
#pragma unroll
                for (int r = 0; r < 4; ++r)
                    sa[obase + (size_t)r * DMODEL + dn * 16 + c] = f2bf(oacc[qs][dn][r] * inv[r]);
        }
    };

    run_seg(qtA, 0, kA1);
    if (w < 2) {
        store_final(qtA);                 // complete q-tile
        run_seg(qtB, 17, kB1);            // tail of the long q-tile (may be empty)
        float* mg = &Mrg[w][lane][0];
#pragma unroll
        for (int qs = 0; qs < 4; ++qs) {
#pragma unroll
            for (int dn = 0; dn < 4; ++dn)
#pragma unroll
                for (int r = 0; r < 4; ++r) mg[qs * 16 + dn * 4 + r] = oacc[qs][dn][r];
#pragma unroll
            for (int r = 0; r < 4; ++r) mg[64 + qs * 4 + r] = lacc[qs][r];
        }
    }
    __syncthreads();                      // convergent: all 4 waves, exactly once
    if (w >= 2) {
        const float* mg = &Mrg[3 - w][lane][0];   // w=2 <- wave1's tail; w=3 <- wave0's
#pragma unroll
        for (int qs = 0; qs < 4; ++qs) {
#pragma unroll
            for (int dn = 0; dn < 4; ++dn)
#pragma unroll
                for (int r = 0; r < 4; ++r) oacc[qs][dn][r] += mg[qs * 16 + dn * 4 + r];
#pragma unroll
            for (int r = 0; r < 4; ++r) lacc[qs][r] += mg[64 + qs * 4 + r];
        }
        store_final(qtA);
    }
}

extern "C" void kernel_launch(void* const* d_in, const int* in_sizes, int n_in,
                              void* d_out, int out_size, void* d_ws, size_t ws_size,
                              hipStream_t stream) {
    const float* x     = (const float*)d_in[0];
    const float* Wkqv  = (const float*)d_in[1];
    const float* bkqv  = (const float*)d_in[2];
    const float* Wproj = (const float*)d_in[3];
    const float* bproj = (const float*)d_in[4];
    float* out = (float*)d_out;

    unsigned short* Kb = (unsigned short*)d_ws;        // [64][2048][64]
    unsigned short* Qb = Kb + (size_t)8388608;         // [64][2048][64]
    unsigned short* VT = Qb + (size_t)8388608;         // [64][64][2048]
    unsigned short* sa = VT + (size_t)8388608;         // [8192][1024]

    const bool fast = ws_size >= 75497472ull;          // 72 MiB
    if (fast) {
        unsigned short* xb  = sa;                      // xb dead before attn writes sa
        unsigned short* wkb = (unsigned short*)d_ws + (size_t)33554432;
        unsigned short* wpb = wkb + (size_t)3145728;
        cvt_bf16<<<12288, 256, 0, stream>>>(x, Wkqv, Wproj, xb, wkb, wpb);
        gemm_lds<1><<<dim3(12, 64), 512, 0, stream>>>(
            xb, wkb, bkqv, nullptr, Kb, Qb, VT, 8192, 3072, 1024);
        attn_mfma<<<512, 256, 0, stream>>>(Kb, Qb, VT, sa);
        gemm_lds<2><<<dim3(4, 64), 512, 0, stream>>>(
            sa, wpb, bproj, out, nullptr, nullptr, nullptr, 8192, 1024, 1024);
    } else {
        gemm_mfma<false, 1><<<dim3(24, 64), 256, 0, stream>>>(
            x, Wkqv, bkqv, nullptr, Kb, Qb, VT, 8192, 3072, 1024);
        attn_mfma<<<512, 256, 0, stream>>>(Kb, Qb, VT, sa);
        gemm_mfma<true, 2><<<dim3(8, 64), 256, 0, stream>>>(
            sa, Wproj, bproj, out, nullptr, nullptr, nullptr, 8192, 1024, 1024);
    }
}

// Round 12
// 270.605 us; speedup vs baseline: 1.3181x; 1.3181x over previous
//
#include <hip/hip_runtime.h>
#include <hip/hip_bf16.h>

// CausalSelfAttention: B=4, N=2048, D=1024, H=16, HD=64. fp32 in / fp32 out.
// R19 = R13 exact restore (best measured 270.6us). R18's attn K-prefetch spilled
//      (VGPR capped 128, scratch FETCH 186MB/WRITE 398MB) — reverted. gemm1 =
//      128x256/8-wave/3-slot ring/768 blocks; gemm2 = gemm_lds<2> @ 4x64;
//      attn = R12 balanced split-K; cvt unchanged.
// ws: Kb/Qb/VT/sa 4x16.78MB = 64MiB; fast path adds wkb+wpb -> 72MiB; xb overlaps sa.

#define NSEQ 2048
#define NHEAD 16
#define DMODEL 1024
#define SCALE2 0.18033688011112042f  // 0.125 * log2(e)

typedef __attribute__((ext_vector_type(8))) short v8s;  // 8 bf16 = 4 VGPRs
typedef __attribute__((ext_vector_type(4))) float v4f;  // MFMA acc

__device__ __forceinline__ float bf2f(unsigned short u) {
    union { unsigned int i; float f; } v;
    v.i = ((unsigned int)u) << 16;
    return v.f;
}
__device__ __forceinline__ unsigned short f2bf(float f) {  // RNE
    unsigned int x = __float_as_uint(f);
    return (unsigned short)((x + 0x7fffu + ((x >> 16) & 1u)) >> 16);
}
__device__ __forceinline__ unsigned short f2bf_rh(float f) {  // round-half-up
    return (unsigned short)((__float_as_uint(f) + 0x8000u) >> 16);
}
__device__ __forceinline__ float fast_exp2(float x) {
#if __has_builtin(__builtin_amdgcn_exp2f)
    return __builtin_amdgcn_exp2f(x);
#else
    return __expf(x * 0.69314718056f);
#endif
}
__device__ __forceinline__ void gld_lds16(const unsigned short* g, unsigned short* l) {
    __builtin_amdgcn_global_load_lds(
        (const __attribute__((address_space(1))) void*)g,
        (__attribute__((address_space(3))) void*)l, 16, 0, 0);
}

// ---------------- cvt: fp32 -> bf16 for x, Wkqv (class-major permute), Wproj -------
// Wkqv in rows h*192 + cls*64 + e -> wkb rows cls*1024 + h*64 + e.
__global__ __launch_bounds__(256) void cvt_bf16(
    const float* __restrict__ x, const float* __restrict__ wk, const float* __restrict__ wp,
    unsigned short* __restrict__ xb, unsigned short* __restrict__ wkb,
    unsigned short* __restrict__ wpb)
{
    const int i = blockIdx.x * 256 + threadIdx.x;   // quad index, 3145728 total
    const float* s; unsigned short* d; int o;
    if (i < 2097152)      { s = x;  d = xb;  o = i; }
    else if (i < 2883584) {
        s = wk; d = wkb;
        const int oi  = i - 2097152;          // 0..786431
        const int row = oi >> 8, cq = oi & 255;
        const int h   = row / 192;
        const int rem = row - h * 192;
        const int cls = rem >> 6, e = rem & 63;
        float4 f = ((const float4*)s)[oi];
        ushort4 u;
        u.x = f2bf(f.x); u.y = f2bf(f.y); u.z = f2bf(f.z); u.w = f2bf(f.w);
        ((ushort4*)d)[(((cls << 10) + (h << 6) + e) << 8) + cq] = u;
        return;
    }
    else                  { s = wp; d = wpb; o = i - 2883584; }
    float4 f = ((const float4*)s)[o];
    ushort4 u;
    u.x = f2bf(f.x); u.y = f2bf(f.y); u.z = f2bf(f.z); u.w = f2bf(f.w);
    ((ushort4*)d)[o] = u;
}

// ---------------- fast MFMA GEMM: 128x256 tile, 3-slot ring, 2 blocks/CU ----------
// C[M,Nc] = A[M,K] @ B[Nc,K]^T + bias. 512 thr = 8 waves (2Mx4N), per-wave 64x64.
// LDS ring: 3 slots x (A 8KB + B 16KB) = 72KB -> 2 blocks/CU. Stage tile t+2 while
// computing t; single barrier per K-step; counted vmcnt(3) (never 0 until tail).
// Requires gridDim.y == 64, grid total % 8 == 0, K >= 64.
// EPI=1: B is class-major-permuted kqv weights; split-write Kb/Qb(scaled)/VT.
// EPI=2: plain fp32 C.
template <int EPI>
__global__ __launch_bounds__(512, 4) void gemm_lds(
    const unsigned short* __restrict__ A, const unsigned short* __restrict__ B,
    const float* __restrict__ bias,
    float* __restrict__ Cf,
    unsigned short* __restrict__ Kb, unsigned short* __restrict__ Qb,
    unsigned short* __restrict__ VTb,
    int M, int Nc, int K)
{
    __shared__ __align__(16) unsigned short Al[3][4096];   // 128 rows x 32k
    __shared__ __align__(16) unsigned short Bl[3][8192];   // 256 rows x 32k

    const int t = threadIdx.x, wave = t >> 6, lane = t & 63;
    const int wm = wave >> 2, wn = wave & 3;               // 2 x 4 wave grid

    // XCD-chunked bijective swizzle: per XCD an 8-row A slab (2MB) x all bx;
    // B tile (512KB) reused 8x within the XCD's L2.
    const int lin = blockIdx.y * gridDim.x + blockIdx.x;
    const int xcd = lin & 7, pos = lin >> 3;
    const int by  = (xcd << 3) + (pos & 7);
    const int bx  = pos >> 3;
    const int m0 = by * 128, n0 = bx * 256;
    const int quad = lane >> 4, c = lane & 15;

    // staging: wave w loads A 16-row group w, B groups {2w, 2w+1}.
    const int r15 = lane & 15, kg = (lane >> 4) & 3;
    const int g0 = wave * 2, g1 = wave * 2 + 1;
    const unsigned short* sA  = A + (size_t)(m0 + wave * 16 + r15) * K + kg * 8;
    const unsigned short* sB0 = B + (size_t)(n0 + g0 * 16 + r15) * K + kg * 8;
    const unsigned short* sB1 = B + (size_t)(n0 + g1 * 16 + r15) * K + kg * 8;

    v4f acc[4][4];
#pragma unroll
    for (int i = 0; i < 4; ++i)
#pragma unroll
        for (int j = 0; j < 4; ++j) acc[i][j] = (v4f){0.f, 0.f, 0.f, 0.f};

    const int fbase = (quad * 16 + c) * 8;
    const int nt = K >> 5;   // 32-wide K tiles (K=1024 -> 32)

    auto stage = [&](int sl, int tt) {
        const int o = tt << 5;
        gld_lds16(sA  + o, &Al[sl][wave * 512]);
        gld_lds16(sB0 + o, &Bl[sl][g0 * 512]);
        gld_lds16(sB1 + o, &Bl[sl][g1 * 512]);
    };

    // prologue: tiles 0,1 staged (6 loads/thread); wait tile 0 (leave 3 in flight)
    stage(0, 0);
    stage(1, 1);
    asm volatile("s_waitcnt vmcnt(3)" ::: "memory");
    __builtin_amdgcn_s_barrier();

    int sl = 0;
    for (int tt = 0; tt < nt; ++tt) {
        const int sl2 = (sl == 0) ? 2 : sl - 1;   // (tt+2)%3
        const bool pf = (tt + 2 < nt);

        v8s af[4], bfr[4];
#pragma unroll
        for (int ms = 0; ms < 4; ++ms)
            af[ms] = *(const v8s*)&Al[sl][(wm * 4 + ms) * 512 + fbase];
#pragma unroll
        for (int ns = 0; ns < 4; ++ns)
            bfr[ns] = *(const v8s*)&Bl[sl][(wn * 4 + ns) * 512 + fbase];
        if (pf) stage(sl2, tt + 2);               // overlaps MFMA below

        __builtin_amdgcn_s_setprio(1);
#pragma unroll
        for (int ms = 0; ms < 4; ++ms)
#pragma unroll
            for (int ns = 0; ns < 4; ++ns)
                acc[ms][ns] = __builtin_amdgcn_mfma_f32_16x16x32_bf16(
                    af[ms], bfr[ns], acc[ms][ns], 0, 0, 0);
        __builtin_amdgcn_s_setprio(0);

        // retire tile tt+1's 3 loads; tile tt+2's stay in flight across the barrier
        if (pf) { asm volatile("s_waitcnt vmcnt(3)" ::: "memory"); }
        else    { asm volatile("s_waitcnt vmcnt(0)" ::: "memory"); }
        __builtin_amdgcn_s_barrier();
        sl = (sl == 2) ? 0 : sl + 1;
    }

#pragma unroll
    for (int ms = 0; ms < 4; ++ms) {
        const int row0 = m0 + wm * 64 + ms * 16 + quad * 4;
#pragma unroll
        for (int ns = 0; ns < 4; ++ns) {
            const int colbase = n0 + wn * 64 + ns * 16;   // wave-uniform, 16-aligned
            float bn, scl = 1.f;
            if (EPI == 2) {
                bn = bias[colbase + c];
            } else {
                const int cls = colbase >> 10;
                const int wi  = colbase & 1023;
                const int h   = wi >> 6, e0 = wi & 63;
                bn = bias[h * 192 + cls * 64 + e0 + c];
                if (cls == 1) scl = SCALE2;
            }
            float v0 = (acc[ms][ns][0] + bn) * scl;
            float v1 = (acc[ms][ns][1] + bn) * scl;
            float v2 = (acc[ms][ns][2] + bn) * scl;
            float v3 = (acc[ms][ns][3] + bn) * scl;
            if (EPI == 2) {
                float* pc = Cf + (size_t)row0 * Nc + colbase + c;
                pc[0] = v0; pc[(size_t)Nc] = v1;
                pc[(size_t)2 * Nc] = v2; pc[(size_t)3 * Nc] = v3;
            } else {
                const int cls = colbase >> 10;
                const int wi  = colbase & 1023;
                const int h   = wi >> 6, e = (wi & 63) + c;
                const int bb  = row0 >> 11, tok0 = row0 & 2047;
                const int bhh = bb * 16 + h;
                if (cls == 2) {            // V -> transposed [bh][dim][tok]
                    ushort4 pk;
                    pk.x = f2bf(v0); pk.y = f2bf(v1); pk.z = f2bf(v2); pk.w = f2bf(v3);
                    *(ushort4*)(VTb + ((size_t)bhh * 64 + e) * 2048 + tok0) = pk;
                } else {                   // K or Q -> [bh][tok][dim]
                    unsigned short* dst = (cls == 0) ? Kb : Qb;
                    const size_t base = ((size_t)bhh * 2048 + tok0) * 64 + e;
                    dst[base]       = f2bf(v0);
                    dst[base + 64]  = f2bf(v1);
                    dst[base + 128] = f2bf(v2);
                    dst[base + 192] = f2bf(v3);
                }
            }
        }
    }
}

// ---------------- fallback GEMM (fp32 sources, VGPR-roundtrip staging) -------------
// EPI=1 uses ORIGINAL (unpermuted) Wkqv col mapping h*192+e; scales Q by SCALE2.
template <bool A_BF16, int EPI>
__global__ __launch_bounds__(256) void gemm_mfma(
    const void* __restrict__ Av, const float* __restrict__ B,
    const float* __restrict__ bias,
    float* __restrict__ Cf,
    unsigned short* __restrict__ Kb, unsigned short* __restrict__ Qb,
    unsigned short* __restrict__ VTb,
    int M, int Nc, int K)
{
    __shared__ __align__(16) unsigned short Al[512 * 8];
    __shared__ __align__(16) unsigned short Bl[512 * 8];

    const int t = threadIdx.x;
    const int wave = t >> 6, lane = t & 63;
    const int wm = wave >> 1, wn = wave & 1;
    const int m0 = blockIdx.y * 128, n0 = blockIdx.x * 128;
    const int quad = lane >> 4, c = lane & 15;

    const int srow = t >> 1, skh = t & 1;
    const int sslot = (srow >> 4) * 64 + (skh * 2) * 16 + (srow & 15);

    v4f acc[4][4];
#pragma unroll
    for (int i = 0; i < 4; ++i)
#pragma unroll
        for (int j = 0; j < 4; ++j) acc[i][j] = (v4f){0.f, 0.f, 0.f, 0.f};

    const unsigned short* pa_u = (const unsigned short*)Av + (size_t)(m0 + srow) * K + skh * 16;
    const float*          pa_f = (const float*)Av          + (size_t)(m0 + srow) * K + skh * 16;
    const float*          pb   = B                          + (size_t)(n0 + srow) * K + skh * 16;

    const int fbase = (quad * 16 + c) * 8;

    for (int k0 = 0; k0 < K; k0 += 32) {
        unsigned short a16[16], b16[16];
        if (A_BF16) {
            uint4 r0 = *(const uint4*)(pa_u + k0);
            uint4 r1 = *(const uint4*)(pa_u + k0 + 8);
            *(uint4*)&a16[0] = r0; *(uint4*)&a16[8] = r1;
        } else {
            float4 f0 = *(const float4*)(pa_f + k0);
            float4 f1 = *(const float4*)(pa_f + k0 + 4);
            float4 f2 = *(const float4*)(pa_f + k0 + 8);
            float4 f3 = *(const float4*)(pa_f + k0 + 12);
            a16[0] = f2bf_rh(f0.x); a16[1] = f2bf_rh(f0.y); a16[2] = f2bf_rh(f0.z); a16[3] = f2bf_rh(f0.w);
            a16[4] = f2bf_rh(f1.x); a16[5] = f2bf_rh(f1.y); a16[6] = f2bf_rh(f1.z); a16[7] = f2bf_rh(f1.w);
            a16[8] = f2bf_rh(f2.x); a16[9] = f2bf_rh(f2.y); a16[10] = f2bf_rh(f2.z); a16[11] = f2bf_rh(f2.w);
            a16[12] = f2bf_rh(f3.x); a16[13] = f2bf_rh(f3.y); a16[14] = f2bf_rh(f3.z); a16[15] = f2bf_rh(f3.w);
        }
        {
            float4 g0 = *(const float4*)(pb + k0);
            float4 g1 = *(const float4*)(pb + k0 + 4);
            float4 g2 = *(const float4*)(pb + k0 + 8);
            float4 g3 = *(const float4*)(pb + k0 + 12);
            b16[0] = f2bf_rh(g0.x); b16[1] = f2bf_rh(g0.y); b16[2] = f2bf_rh(g0.z); b16[3] = f2bf_rh(g0.w);
            b16[4] = f2bf_rh(g1.x); b16[5] = f2bf_rh(g1.y); b16[6] = f2bf_rh(g1.z); b16[7] = f2bf_rh(g1.w);
            b16[8] = f2bf_rh(g2.x); b16[9] = f2bf_rh(g2.y); b16[10] = f2bf_rh(g2.z); b16[11] = f2bf_rh(g2.w);
            b16[12] = f2bf_rh(g3.x); b16[13] = f2bf_rh(g3.y); b16[14] = f2bf_rh(g3.z); b16[15] = f2bf_rh(g3.w);
        }
        __syncthreads();
        *(uint4*)&Al[sslot * 8]        = *(uint4*)&a16[0];
        *(uint4*)&Al[(sslot + 16) * 8] = *(uint4*)&a16[8];
        *(uint4*)&Bl[sslot * 8]        = *(uint4*)&b16[0];
        *(uint4*)&Bl[(sslot + 16) * 8] = *(uint4*)&b16[8];
        __syncthreads();

        v8s af[4], bf[4];
#pragma unroll
        for (int ms = 0; ms < 4; ++ms)
            af[ms] = *(const v8s*)&Al[(wm * 4 + ms) * 512 + fbase];
#pragma unroll
        for (int ns = 0; ns < 4; ++ns)
            bf[ns] = *(const v8s*)&Bl[(wn * 4 + ns) * 512 + fbase];
#pragma unroll
        for (int ms = 0; ms < 4; ++ms)
#pragma unroll
            for (int ns = 0; ns < 4; ++ns)
                acc[ms][ns] = __builtin_amdgcn_mfma_f32_16x16x32_bf16(
                    af[ms], bf[ns], acc[ms][ns], 0, 0, 0);
    }

#pragma unroll
    for (int ms = 0; ms < 4; ++ms) {
        const int row0 = m0 + wm * 64 + ms * 16 + quad * 4;
#pragma unroll
        for (int ns = 0; ns < 4; ++ns) {
            const int colbase = n0 + wn * 64 + ns * 16;
            float bn = (EPI == 2) ? bias[colbase + c] : bias[colbase + c];
            float v0 = acc[ms][ns][0] + bn;
            float v1 = acc[ms][ns][1] + bn;
            float v2 = acc[ms][ns][2] + bn;
            float v3 = acc[ms][ns][3] + bn;
            if (EPI == 2) {
                float* pc = Cf + (size_t)row0 * Nc + colbase + c;
                pc[0] = v0; pc[(size_t)Nc] = v1;
                pc[(size_t)2 * Nc] = v2; pc[(size_t)3 * Nc] = v3;
            } else {
                const int hh = colbase / 192;
                const int eb = colbase - hh * 192;
                const int bb = row0 >> 11, tok0 = row0 & 2047;
                const int bhh = bb * 16 + hh;
                if (eb >= 128) {
                    ushort4 pk;
                    pk.x = f2bf(v0); pk.y = f2bf(v1); pk.z = f2bf(v2); pk.w = f2bf(v3);
                    *(ushort4*)(VTb + ((size_t)bhh * 64 + (eb - 128) + c) * 2048 + tok0) = pk;
                } else {
                    const bool isq = (eb >= 64);
                    const float s = isq ? SCALE2 : 1.f;
                    unsigned short* dst = isq ? Qb : Kb;
                    const int e = (isq ? eb - 64 : eb) + c;
                    const size_t base = ((size_t)bhh * 2048 + tok0) * 64 + e;
                    dst[base]       = f2bf(v0 * s);
                    dst[base + 64]  = f2bf(v1 * s);
                    dst[base + 128] = f2bf(v2 * s);
                    dst[base + 192] = f2bf(v3 * s);
                }
            }
        }
    }
}

// ---------------- balanced split-K MFMA flash attention, constant-m softmax -------
// grid 512 x 256thr. bh = blockIdx&63 (XCD-grouped), bq = blockIdx>>6 (0..7).
// Constant-m softmax (P = exp2(s) raw, |s|<=46) => split-K partials just add.
// wave0: qt=bq [0,bq+1) complete + qt=31-bq [17,32-bq) tail      -> 16 kt
// wave1: qt=15-bq [0,16-bq) complete + qt=16+bq [17,17+bq) tail  -> 16 kt
// wave2: qt=16+bq [0,17) head, merges wave1's tail               -> 17 kt
// wave3: qt=31-bq [0,17) head, merges wave0's tail               -> 17 kt
// Merge via Mrg LDS (stride 81 floats -> conflict-free), one convergent barrier.
#define ATTS 72

__global__ __launch_bounds__(256, 2) void attn_mfma(
    const unsigned short* __restrict__ Kbuf,  // [64][2048][64]
    const unsigned short* __restrict__ Qbuf,  // [64][2048][64] (scaled)
    const unsigned short* __restrict__ VT,    // [64][64][2048]
    unsigned short* __restrict__ sa)          // [8192][1024]
{
    __shared__ __align__(16) unsigned short Ps[4][64 * ATTS];   // 36,864 B
    __shared__ __align__(16) float Mrg[2][64][81];              // 41,472 B

    const int t = threadIdx.x, w = t >> 6, lane = t & 63;
    const int quad = lane >> 4, c = lane & 15;
    const int bh = blockIdx.x & 63, bq = blockIdx.x >> 6;
    const int b = bh >> 4, hh = bh & 15;
    const size_t gbase = (size_t)bh * (2048 * 64);

    const int rs  = c & 3;
    const int rc0 = (quad ^ rs) * 8, rc1 = 32 + rc0;
    unsigned short* PsW = &Ps[w][0];

    // balanced segment table (see header comment)
    const int qtA = (w == 0) ? bq : (w == 1) ? (15 - bq) : (w == 2) ? (16 + bq) : (31 - bq);
    const int kA1 = (w == 0) ? (bq + 1) : (w == 1) ? (16 - bq) : 17;
    const int qtB = (w == 0) ? (31 - bq) : (16 + bq);   // waves 0/1 only
    const int kB1 = (w == 0) ? (32 - bq) : (17 + bq);

    v4f oacc[4][4], lacc[4];
    const short oneb = (short)0x3F80;  // bf16 1.0
    const v8s ones = {oneb, oneb, oneb, oneb, oneb, oneb, oneb, oneb};

    auto run_seg = [&](int qt, int k0, int k1) {
        const int qw = qt * 64;
        v8s qf[4][2];
#pragma unroll
        for (int qs = 0; qs < 4; ++qs) {
            const unsigned short* qp =
                Qbuf + gbase + (size_t)(qw + qs * 16 + c) * 64 + quad * 8;
            qf[qs][0] = *(const v8s*)qp;
            qf[qs][1] = *(const v8s*)(qp + 32);
        }
#pragma unroll
        for (int qs = 0; qs < 4; ++qs) {
            lacc[qs] = (v4f){0.f, 0.f, 0.f, 0.f};
#pragma unroll
            for (int dn = 0; dn < 4; ++dn) oacc[qs][dn] = (v4f){0.f, 0.f, 0.f, 0.f};
        }
        for (int kt = k0; kt < k1; ++kt) {
            const int kbase = kt * 64;
            const bool diag = (kt == qt);   // wave-uniform

            // V prefetch (vmcnt FIFO: the K wait also covers V arrival)
            v8s vf[4][2];
#pragma unroll
            for (int dn = 0; dn < 4; ++dn) {
                const unsigned short* vp =
                    VT + gbase + (size_t)(dn * 16 + c) * 2048 + kbase + quad * 8;
                vf[dn][0] = *(const v8s*)vp;
                vf[dn][1] = *(const v8s*)(vp + 32);
            }

            // S = Q K^T, P = exp2(S) streamed into Ps (A-layout via swizzle)
#pragma unroll
            for (int kn = 0; kn < 4; ++kn) {
                const unsigned short* kp =
                    Kbuf + gbase + (size_t)(kbase + kn * 16 + c) * 64 + quad * 8;
                v8s kf0 = *(const v8s*)kp;
                v8s kf1 = *(const v8s*)(kp + 32);
#pragma unroll
                for (int qs = 0; qs < 4; ++qs) {
                    v4f s = (v4f){0.f, 0.f, 0.f, 0.f};
                    s = __builtin_amdgcn_mfma_f32_16x16x32_bf16(qf[qs][0], kf0, s, 0, 0, 0);
                    s = __builtin_amdgcn_mfma_f32_16x16x32_bf16(qf[qs][1], kf1, s, 0, 0, 0);
                    if (diag) {
#pragma unroll
                        for (int r = 0; r < 4; ++r)
                            if (kn * 16 + c > qs * 16 + quad * 4 + r) s[r] = -1e30f;
                    }
#pragma unroll
                    for (int r = 0; r < 4; ++r) {
                        const float p = fast_exp2(s[r]);
                        PsW[(qs * 16 + quad * 4 + r) * ATTS +
                            (((2 * kn + (c >> 3)) ^ r) * 8) + (c & 7)] = f2bf_rh(p);
                    }
                }
            }
            // P fragments (A-layout), then O += P V and l += P @ ones
            v8s pa[4][2];
#pragma unroll
            for (int qs = 0; qs < 4; ++qs) {
                pa[qs][0] = *(const v8s*)&PsW[(qs * 16 + c) * ATTS + rc0];
                pa[qs][1] = *(const v8s*)&PsW[(qs * 16 + c) * ATTS + rc1];
            }
#pragma unroll
            for (int dn = 0; dn < 4; ++dn) {
#pragma unroll
                for (int qs = 0; qs < 4; ++qs) {
                    oacc[qs][dn] = __builtin_amdgcn_mfma_f32_16x16x32_bf16(pa[qs][0], vf[dn][0], oacc[qs][dn], 0, 0, 0);
                    oacc[qs][dn] = __builtin_amdgcn_mfma_f32_16x16x32_bf16(pa[qs][1], vf[dn][1], oacc[qs][dn], 0, 0, 0);
                }
            }
#pragma unroll
            for (int qs = 0; qs < 4; ++qs) {
                lacc[qs] = __builtin_amdgcn_mfma_f32_16x16x32_bf16(pa[qs][0], ones, lacc[qs], 0, 0, 0);
                lacc[qs] = __builtin_amdgcn_mfma_f32_16x16x32_bf16(pa[qs][1], ones, lacc[qs], 0, 0, 0);
            }
        }
    };

    auto store_final = [&](int qt) {
        const int qw = qt * 64;
#pragma unroll
        for (int qs = 0; qs < 4; ++qs) {
            float inv[4];
#pragma unroll
            for (int r = 0; r < 4; ++r) inv[r] = 1.f / lacc[qs][r];
            const size_t obase =
                ((size_t)(b * 2048 + qw + qs * 16 + quad * 4)) * DMODEL + hh * 64;
#pragma unroll
            for (int dn = 0; dn < 4; ++dn)
#pragma unroll
                for (int r = 0; r < 4; ++r)
                    sa[obase + (size_t)r * DMODEL + dn * 16 + c] = f2bf(oacc[qs][dn][r] * inv[r]);
        }
    };

    run_seg(qtA, 0, kA1);
    if (w < 2) {
        store_final(qtA);                 // complete q-tile
        run_seg(qtB, 17, kB1);            // tail of the long q-tile (may be empty)
        float* mg = &Mrg[w][lane][0];
#pragma unroll
        for (int qs = 0; qs < 4; ++qs) {
#pragma unroll
            for (int dn = 0; dn < 4; ++dn)
#pragma unroll
                for (int r = 0; r < 4; ++r) mg[qs * 16 + dn * 4 + r] = oacc[qs][dn][r];
#pragma unroll
            for (int r = 0; r < 4; ++r) mg[64 + qs * 4 + r] = lacc[qs][r];
        }
    }
    __syncthreads();                      // convergent: all 4 waves, exactly once
    if (w >= 2) {
        const float* mg = &Mrg[3 - w][lane][0];   // w=2 <- wave1's tail; w=3 <- wave0's
#pragma unroll
        for (int qs = 0; qs < 4; ++qs) {
#pragma unroll
            for (int dn = 0; dn < 4; ++dn)
#pragma unroll
                for (int r = 0; r < 4; ++r) oacc[qs][dn][r] += mg[qs * 16 + dn * 4 + r];
#pragma unroll
            for (int r = 0; r < 4; ++r) lacc[qs][r] += mg[64 + qs * 4 + r];
        }
        store_final(qtA);
    }
}

extern "C" void kernel_launch(void* const* d_in, const int* in_sizes, int n_in,
                              void* d_out, int out_size, void* d_ws, size_t ws_size,
                              hipStream_t stream) {
    const float* x     = (const float*)d_in[0];
    const float* Wkqv  = (const float*)d_in[1];
    const float* bkqv  = (const float*)d_in[2];
    const float* Wproj = (const float*)d_in[3];
    const float* bproj = (const float*)d_in[4];
    float* out = (float*)d_out;

    unsigned short* Kb = (unsigned short*)d_ws;        // [64][2048][64]
    unsigned short* Qb = Kb + (size_t)8388608;         // [64][2048][64]
    unsigned short* VT = Qb + (size_t)8388608;         // [64][64][2048]
    unsigned short* sa = VT + (size_t)8388608;         // [8192][1024]

    const bool fast = ws_size >= 75497472ull;          // 72 MiB
    if (fast) {
        unsigned short* xb  = sa;                      // xb dead before attn writes sa
        unsigned short* wkb = (unsigned short*)d_ws + (size_t)33554432;
        unsigned short* wpb = wkb + (size_t)3145728;
        cvt_bf16<<<12288, 256, 0, stream>>>(x, Wkqv, Wproj, xb, wkb, wpb);
        gemm_lds<1><<<dim3(12, 64), 512, 0, stream>>>(
            xb, wkb, bkqv, nullptr, Kb, Qb, VT, 8192, 3072, 1024);
        attn_mfma<<<512, 256, 0, stream>>>(Kb, Qb, VT, sa);
        gemm_lds<2><<<dim3(4, 64), 512, 0, stream>>>(
            sa, wpb, bproj, out, nullptr, nullptr, nullptr, 8192, 1024, 1024);
    } else {
        gemm_mfma<false, 1><<<dim3(24, 64), 256, 0, stream>>>(
            x, Wkqv, bkqv, nullptr, Kb, Qb, VT, 8192, 3072, 1024);
        attn_mfma<<<512, 256, 0, stream>>>(Kb, Qb, VT, sa);
        gemm_mfma<true, 2><<<dim3(8, 64), 256, 0, stream>>>(
            sa, Wproj, bproj, out, nullptr, nullptr, nullptr, 8192, 1024, 1024);
    }
}